// Round 2
// baseline (17806.487 us; speedup 1.0000x reference)
//
#include <hip/hip_runtime.h>
#include <hip/hip_fp16.h>
#include <cstddef>

using half_t = __half;

#define T_SEQ 512
#define B_SZ  128
#define H_SZ  200
#define D_EMB 50
#define K_TAGS 25

__device__ __forceinline__ float sigmoidf_(float x) {
  x = fminf(fmaxf(x, -30.f), 30.f);
  return 1.f / (1.f + __expf(-x));
}
__device__ __forceinline__ float tanhf_(float x) {
  x = fminf(fmaxf(x, -15.f), 15.f);
  float e = __expf(2.f * x);
  return (e - 1.f) / (e + 1.f);
}

// x0[(t*128+b)*50 + d] = emb[x[b][t]][d]
__global__ __launch_bounds__(256) void embed_kernel(const int* __restrict__ x,
                                                    const float* __restrict__ emb,
                                                    half_t* __restrict__ x0) {
  int idx = blockIdx.x * 256 + threadIdx.x;
  if (idx >= T_SEQ * B_SZ * D_EMB) return;
  int d  = idx % D_EMB;
  int tb = idx / D_EMB;
  int b  = tb % B_SZ;
  int t  = tb / B_SZ;
  int tok = x[b * T_SEQ + t];
  x0[idx] = __float2half(emb[(size_t)tok * D_EMB + d]);
}

// bsum[layer][dir*800+g] = b[dir][0][g] + b[dir][1][g], flattened [2][1600]
__global__ __launch_bounds__(256) void bsum_kernel(const float* __restrict__ b0,
                                                   const float* __restrict__ b1,
                                                   float* __restrict__ bsum) {
  int i = blockIdx.x * 256 + threadIdx.x;
  if (i >= 3200) return;
  const float* src = (i < 1600) ? b0 : b1;
  int j = (i < 1600) ? i : (i - 1600);
  int dir = j / 800, g = j % 800;
  bsum[i] = src[dir * 1600 + g] + src[dir * 1600 + 800 + g];
}

__global__ __launch_bounds__(256) void zero_kernel(float* __restrict__ p, int n) {
  int i = blockIdx.x * 256 + threadIdx.x;
  if (i < n) p[i] = 0.f;
}

// xw chunk GEMM: for chunk q of size C, both directions.
// chunk[((dir*C+tq)*128 + b)*800 + n] = sum_k A[(t*128+b)*Kin + k] * Wih[(dir*800+n)*Kin + k] + bsumL[dir*800+n]
// where t = dir ? (511 - q*C - tq) : (q*C + tq).
// grid (13 n-tiles, 2*C), block 256; 128(b) x 64(n) tile, 8x4 per thread.
__global__ __launch_bounds__(256) void xw_gemm_kernel(const half_t* __restrict__ A,
                                                      const float* __restrict__ Wih,
                                                      const float* __restrict__ bsumL,
                                                      half_t* __restrict__ chunk,
                                                      int Kin, int C, int q) {
  __shared__ __align__(16) float As2[16][132];
  __shared__ __align__(16) float Bs2[16][68];
  const int tid = threadIdx.x;
  const int dirTq = blockIdx.y;
  const int dir = dirTq / C;
  const int tq  = dirTq - dir * C;
  const int t = dir ? (T_SEQ - 1 - q * C - tq) : (q * C + tq);
  const int n0 = blockIdx.x * 64;
  const int tm = tid >> 4, tn = tid & 15;
  const size_t arow0 = (size_t)t * B_SZ * Kin;
  float acc[8][4] = {};
  for (int k0 = 0; k0 < Kin; k0 += 16) {
#pragma unroll
    for (int l = 0; l < 8; ++l) {
      int e = tid + l * 256;
      int i = e >> 4, kk = e & 15;
      int k = k0 + kk;
      As2[kk][i] = (k < Kin) ? __half2float(A[arow0 + (size_t)i * Kin + k]) : 0.f;
    }
#pragma unroll
    for (int l = 0; l < 4; ++l) {
      int e = tid + l * 256;
      int j = e >> 4, kk = e & 15;
      int k = k0 + kk, n = n0 + j;
      Bs2[kk][j] = (k < Kin && n < 800) ? Wih[((size_t)dir * 800 + n) * Kin + k] : 0.f;
    }
    __syncthreads();
#pragma unroll
    for (int kk = 0; kk < 16; ++kk) {
      float4 a0 = *(const float4*)&As2[kk][tm * 8];
      float4 a1 = *(const float4*)&As2[kk][tm * 8 + 4];
      float4 bv = *(const float4*)&Bs2[kk][tn * 4];
      float ar[8] = {a0.x, a0.y, a0.z, a0.w, a1.x, a1.y, a1.z, a1.w};
      float bc[4] = {bv.x, bv.y, bv.z, bv.w};
#pragma unroll
      for (int r = 0; r < 8; ++r)
#pragma unroll
        for (int c = 0; c < 4; ++c) acc[r][c] += ar[r] * bc[c];
    }
    __syncthreads();
  }
#pragma unroll
  for (int r = 0; r < 8; ++r) {
    int b = tm * 8 + r;
    size_t obase = ((size_t)dirTq * B_SZ + b) * 800;
#pragma unroll
    for (int c = 0; c < 4; ++c) {
      int n = n0 + tn * 4 + c;
      if (n < 800) chunk[obase + n] = __float2half(acc[r][c] + bsumL[dir * 800 + n]);
    }
  }
}

// One recurrence step, both directions. grid (13 j-tiles, 8 b-tiles, 2 dirs), 256 thr.
// chunk: [dir*C + sc][b][800] (gate-major: g = gate*200 + j). h ping-pong fp32 [2][128][200].
__global__ __launch_bounds__(256) void lstm_step_kernel(const half_t* __restrict__ chunk,
                                                        const float* __restrict__ whh,
                                                        const float* __restrict__ h_prev,
                                                        float* __restrict__ h_next,
                                                        float* __restrict__ c_state,
                                                        half_t* __restrict__ hbuf,
                                                        int s, int sc, int C) {
  const int dir = blockIdx.z;
  const int b0 = blockIdx.y * 16;
  const int j0 = blockIdx.x * 16;
  const int tid = threadIdx.x;
  const int bi = tid & 15, ji = tid >> 4;
  const int t = dir ? (T_SEQ - 1 - s) : s;

  __shared__ __align__(16) float hs[16][204];
  for (int idx = tid; idx < 16 * H_SZ; idx += 256) {
    int bb = idx / H_SZ, kk = idx - bb * H_SZ;
    hs[bb][kk] = h_prev[(size_t)(dir * B_SZ + b0 + bb) * H_SZ + kk];
  }
  __syncthreads();

  const int j = j0 + ji;
  if (j >= H_SZ) return;
  const int b = b0 + bi;

  size_t xwbase = ((size_t)(dir * C + sc) * B_SZ + b) * 800 + j;
  float acc0 = __half2float(chunk[xwbase]);
  float acc1 = __half2float(chunk[xwbase + 200]);
  float acc2 = __half2float(chunk[xwbase + 400]);
  float acc3 = __half2float(chunk[xwbase + 600]);

  const float* w0 = whh + ((size_t)dir * 800 + j) * H_SZ;
  const float4* wr0 = (const float4*)(w0);
  const float4* wr1 = (const float4*)(w0 + 200 * H_SZ);
  const float4* wr2 = (const float4*)(w0 + 400 * H_SZ);
  const float4* wr3 = (const float4*)(w0 + 600 * H_SZ);
  const float4* hp4 = (const float4*)(&hs[bi][0]);
#pragma unroll 5
  for (int k4 = 0; k4 < H_SZ / 4; ++k4) {
    float4 hv = hp4[k4];
    float4 wa = wr0[k4], wb = wr1[k4], wc = wr2[k4], wd = wr3[k4];
    acc0 += hv.x * wa.x + hv.y * wa.y + hv.z * wa.z + hv.w * wa.w;
    acc1 += hv.x * wb.x + hv.y * wb.y + hv.z * wb.z + hv.w * wb.w;
    acc2 += hv.x * wc.x + hv.y * wc.y + hv.z * wc.z + hv.w * wc.w;
    acc3 += hv.x * wd.x + hv.y * wd.y + hv.z * wd.z + hv.w * wd.w;
  }

  float ig = sigmoidf_(acc0);
  float fg = sigmoidf_(acc1);
  float gg = tanhf_(acc2);
  float og = sigmoidf_(acc3);
  size_t sidx = (size_t)(dir * B_SZ + b) * H_SZ + j;
  float c = fg * c_state[sidx] + ig * gg;
  float h = og * tanhf_(c);
  c_state[sidx] = c;
  h_next[sidx] = h;
  hbuf[((size_t)t * B_SZ + b) * 400 + dir * 200 + j] = __float2half(h);
}

// emissions: C[M=65536][N=25] = A[M][400](half) * lin_w[25][400]^T + lin_b
__global__ __launch_bounds__(256) void emis_gemm_kernel(const half_t* __restrict__ A,
                                                        const float* __restrict__ Bw,
                                                        const float* __restrict__ bias,
                                                        float* __restrict__ Cm) {
  __shared__ __align__(16) float As2[16][132];
  __shared__ __align__(16) float Bs2[16][68];
  const int tid = threadIdx.x;
  const int m0 = blockIdx.y * 128;
  const int N = K_TAGS, K = 400;
  const int tm = tid >> 4, tn = tid & 15;
  float acc[8][4] = {};
  for (int k0 = 0; k0 < K; k0 += 16) {
#pragma unroll
    for (int l = 0; l < 8; ++l) {
      int e = tid + l * 256;
      int i = e >> 4, kk = e & 15;
      As2[kk][i] = __half2float(A[(size_t)(m0 + i) * K + k0 + kk]);
    }
#pragma unroll
    for (int l = 0; l < 4; ++l) {
      int e = tid + l * 256;
      int j = e >> 4, kk = e & 15;
      Bs2[kk][j] = (j < N) ? Bw[(size_t)j * K + k0 + kk] : 0.f;
    }
    __syncthreads();
#pragma unroll
    for (int kk = 0; kk < 16; ++kk) {
      float4 a0 = *(const float4*)&As2[kk][tm * 8];
      float4 a1 = *(const float4*)&As2[kk][tm * 8 + 4];
      float4 bv = *(const float4*)&Bs2[kk][tn * 4];
      float ar[8] = {a0.x, a0.y, a0.z, a0.w, a1.x, a1.y, a1.z, a1.w};
      float bc[4] = {bv.x, bv.y, bv.z, bv.w};
#pragma unroll
      for (int r = 0; r < 8; ++r)
#pragma unroll
        for (int c = 0; c < 4; ++c) acc[r][c] += ar[r] * bc[c];
    }
    __syncthreads();
  }
#pragma unroll
  for (int r = 0; r < 8; ++r) {
    size_t m = (size_t)m0 + tm * 8 + r;
#pragma unroll
    for (int c = 0; c < 4; ++c) {
      int n = tn * 4 + c;
      if (n < N) Cm[m * N + n] = acc[r][c] + bias[n];
    }
  }
}

// one block (64 threads) per batch element
__global__ __launch_bounds__(64) void crf_kernel(const float* __restrict__ em,
                                                 const int* __restrict__ y,
                                                 const float* __restrict__ start,
                                                 const float* __restrict__ endv,
                                                 const float* __restrict__ trans,
                                                 float* __restrict__ partial) {
  const int b = blockIdx.x;
  const int lane = threadIdx.x;
  __shared__ float tr[K_TAGS * K_TAGS];
  __shared__ float sc[K_TAGS];
  __shared__ float num_s;
  for (int i = lane; i < K_TAGS * K_TAGS; i += 64) tr[i] = trans[i];
  __syncthreads();

  float acc = 0.f;
  for (int t = 1 + lane; t < T_SEQ; t += 64) {
    int yp = y[b * T_SEQ + t - 1];
    int yt = y[b * T_SEQ + t];
    acc += tr[yp * K_TAGS + yt] + em[((size_t)t * B_SZ + b) * K_TAGS + yt];
  }
#pragma unroll
  for (int off = 32; off; off >>= 1) acc += __shfl_down(acc, off);
  if (lane == 0) {
    int y0 = y[b * T_SEQ];
    int yl = y[b * T_SEQ + T_SEQ - 1];
    acc += start[y0] + em[(size_t)b * K_TAGS + y0] + endv[yl];
    num_s = acc;
  }
  if (lane < K_TAGS) sc[lane] = start[lane] + em[(size_t)b * K_TAGS + lane];
  __syncthreads();

  for (int t = 1; t < T_SEQ; ++t) {
    float nv = 0.f;
    if (lane < K_TAGS) {
      float m = -1e30f;
#pragma unroll
      for (int i = 0; i < K_TAGS; ++i) m = fmaxf(m, sc[i] + tr[i * K_TAGS + lane]);
      float ssum = 0.f;
#pragma unroll
      for (int i = 0; i < K_TAGS; ++i) ssum += __expf(sc[i] + tr[i * K_TAGS + lane] - m);
      nv = em[((size_t)t * B_SZ + b) * K_TAGS + lane] + m + __logf(ssum);
    }
    __syncthreads();
    if (lane < K_TAGS) sc[lane] = nv;
    __syncthreads();
  }

  if (lane == 0) {
    float m = -1e30f;
#pragma unroll
    for (int jj = 0; jj < K_TAGS; ++jj) m = fmaxf(m, sc[jj] + endv[jj]);
    float ssum = 0.f;
#pragma unroll
    for (int jj = 0; jj < K_TAGS; ++jj) ssum += __expf(sc[jj] + endv[jj] - m);
    partial[b] = num_s - (m + __logf(ssum));
  }
}

__global__ __launch_bounds__(64) void reduce_kernel(const float* __restrict__ partial,
                                                    float* __restrict__ out) {
  int lane = threadIdx.x;
  float v = partial[lane] + partial[lane + 64];
#pragma unroll
  for (int off = 32; off; off >>= 1) v += __shfl_down(v, off);
  if (lane == 0) out[0] = v;
}

extern "C" void kernel_launch(void* const* d_in, const int* in_sizes, int n_in,
                              void* d_out, int out_size, void* d_ws, size_t ws_size,
                              hipStream_t stream) {
  (void)in_sizes; (void)n_in; (void)out_size;
  const int*   x        = (const int*)d_in[0];
  const int*   y        = (const int*)d_in[1];
  const float* emb      = (const float*)d_in[3];
  const float* w_ih_l0  = (const float*)d_in[4];
  const float* w_hh_l0  = (const float*)d_in[5];
  const float* b_l0     = (const float*)d_in[6];
  const float* w_ih_l1  = (const float*)d_in[7];
  const float* w_hh_l1  = (const float*)d_in[8];
  const float* b_l1     = (const float*)d_in[9];
  const float* lin_w    = (const float*)d_in[10];
  const float* lin_b    = (const float*)d_in[11];
  const float* crf_start= (const float*)d_in[12];
  const float* crf_end  = (const float*)d_in[13];
  const float* crf_trans= (const float*)d_in[14];
  float* out = (float*)d_out;

  char* ws = (char*)d_ws;
  size_t off = 0;
  auto alloc = [&](size_t bytes) {
    size_t r = off;
    off = (off + bytes + 255) & ~(size_t)255;
    return r;
  };
  half_t* x0    = (half_t*)(ws + alloc((size_t)T_SEQ * B_SZ * D_EMB * 2));   // 6.55 MB
  half_t* hbuf0 = (half_t*)(ws + alloc((size_t)T_SEQ * B_SZ * 400 * 2));     // 52.4 MB
  half_t* hbuf1 = (half_t*)(ws + alloc((size_t)T_SEQ * B_SZ * 400 * 2));     // 52.4 MB
  float*  em    = (float*)(ws + alloc((size_t)T_SEQ * B_SZ * K_TAGS * 4));   // 6.55 MB
  float*  bsum  = (float*)(ws + alloc(3200 * 4));
  const int stateN = 3 * 2 * B_SZ * H_SZ;                                     // hA,hB,cS
  float*  stateZ = (float*)(ws + alloc((size_t)stateN * 4));
  float*  hA = stateZ;
  float*  hB = stateZ + 2 * B_SZ * H_SZ;
  float*  cS = stateZ + 4 * B_SZ * H_SZ;
  float*  partial = (float*)(ws + alloc(B_SZ * 4));
  size_t fixedBytes = off;

  // adaptive time-chunk size: chunk buffer = 2*C*128*800*2 bytes = C*409600
  int C = 64;
  while (C > 4 && fixedBytes + (size_t)C * 409600 + (1u << 20) > ws_size) C >>= 1;
  half_t* chunk = (half_t*)(ws + alloc((size_t)2 * C * B_SZ * 800 * 2));

  embed_kernel<<<(T_SEQ * B_SZ * D_EMB + 255) / 256, 256, 0, stream>>>(x, emb, x0);
  bsum_kernel<<<13, 256, 0, stream>>>(b_l0, b_l1, bsum);

  const int nch = T_SEQ / C;
  for (int layer = 0; layer < 2; ++layer) {
    zero_kernel<<<(stateN + 255) / 256, 256, 0, stream>>>(stateZ, stateN);
    const half_t* Ain = layer ? hbuf0 : x0;
    const float* Wih = layer ? w_ih_l1 : w_ih_l0;
    const float* whh = layer ? w_hh_l1 : w_hh_l0;
    const int Kin = layer ? 400 : D_EMB;
    half_t* hb = layer ? hbuf1 : hbuf0;
    float* hp = hA;
    float* hn = hB;
    for (int q = 0; q < nch; ++q) {
      xw_gemm_kernel<<<dim3(13, 2 * C), 256, 0, stream>>>(Ain, Wih, bsum + layer * 1600,
                                                          chunk, Kin, C, q);
      for (int sc = 0; sc < C; ++sc) {
        int s = q * C + sc;
        lstm_step_kernel<<<dim3(13, 8, 2), 256, 0, stream>>>(chunk, whh, hp, hn, cS, hb,
                                                             s, sc, C);
        float* tmp = hp; hp = hn; hn = tmp;
      }
    }
  }

  emis_gemm_kernel<<<dim3(1, 512), 256, 0, stream>>>(hbuf1, lin_w, lin_b, em);
  crf_kernel<<<B_SZ, 64, 0, stream>>>(em, y, crf_start, crf_end, crf_trans, partial);
  reduce_kernel<<<1, 64, 0, stream>>>(partial, out);
}